// Round 3
// baseline (1669.583 us; speedup 1.0000x reference)
//
#include <hip/hip_runtime.h>

#define NN 262144   // nodes
#define NE 1048576  // edges
#define NG 8192     // graphs
#define FD 64       // feature dim
#define AD 8        // adduct dim
#define DN 512      // dense dim

__device__ __forceinline__ int lowerBound(const int* __restrict__ a, int n, int v) {
  int lo = 0, hi = n;
  while (lo < hi) { int mid = (lo + hi) >> 1; if (a[mid] < v) lo = mid + 1; else hi = mid; }
  return lo;
}

// ---------------- CSR build ----------------
__global__ void k_count(const int* __restrict__ dst, int* __restrict__ counts) {
  int e = blockIdx.x * 256 + threadIdx.x;
  if (e < NE) atomicAdd(&counts[dst[e]], 1);
}

__global__ void k_scan1(const int* __restrict__ counts, int* __restrict__ rp,
                        int* __restrict__ bsum) {
  __shared__ int s[256];
  int tid = threadIdx.x;
  int i = blockIdx.x * 256 + tid;
  int orig = counts[i];
  s[tid] = orig;
  __syncthreads();
  for (int off = 1; off < 256; off <<= 1) {
    int v = (tid >= off) ? s[tid - off] : 0;
    __syncthreads();
    s[tid] += v;
    __syncthreads();
  }
  rp[i] = s[tid] - orig;  // block-local exclusive scan
  if (tid == 255) bsum[blockIdx.x] = s[tid];
}

__global__ void k_scan2(int* __restrict__ bsum) {
  __shared__ int s[1024];
  int tid = threadIdx.x;
  int orig = bsum[tid];
  s[tid] = orig;
  __syncthreads();
  for (int off = 1; off < 1024; off <<= 1) {
    int v = (tid >= off) ? s[tid - off] : 0;
    __syncthreads();
    s[tid] += v;
    __syncthreads();
  }
  bsum[tid] = s[tid] - orig;  // exclusive
}

__global__ void k_scan3(const int* __restrict__ counts, int* __restrict__ rp,
                        const int* __restrict__ bsum, int* __restrict__ cursor,
                        float* __restrict__ inv_deg) {
  int i = blockIdx.x * 256 + threadIdx.x;
  int v = rp[i] + bsum[blockIdx.x];
  rp[i] = v;
  cursor[i] = v;
  inv_deg[i] = 1.0f / (float)(counts[i] + 1);
  if (i == 0) rp[NN] = NE;
}

__global__ void k_fill(const int* __restrict__ src, const int* __restrict__ dst,
                       const int* __restrict__ counts, int* __restrict__ cursor,
                       int* __restrict__ csr_src, float* __restrict__ csr_norm) {
  int e = blockIdx.x * 256 + threadIdx.x;
  if (e >= NE) return;
  int s = src[e], d = dst[e];
  float ds = (float)(counts[s] + 1);
  float dd = (float)(counts[d] + 1);
  int pos = atomicAdd(&cursor[d], 1);
  csr_src[pos] = s;
  csr_norm[pos] = rsqrtf(ds * dd);
}

// ---------------- GCN: t = h @ W + b ----------------
// lane = node; row lives in 64 VGPRs (plain float[64], constant indices only
// so SROA promotes it — NO pointer casts, that spilled in R2). W[k][c] is
// wave-uniform -> s_load_dwordx16 per k; inner loop = 16 independent
// v_fmac acc[c], s_w, v_row[k] chains. No LDS.
__global__ void __launch_bounds__(256, 4) k_transform(const float* __restrict__ hin,
                                                      const float* __restrict__ W,
                                                      const float* __restrict__ b,
                                                      float* __restrict__ tout) {
  int n = blockIdx.x * 256 + threadIdx.x;  // one node per thread
  const float4* h4 = (const float4*)(hin + (size_t)n * 64);
  float row[64];
#pragma unroll
  for (int i = 0; i < 16; i++) {
    float4 v = h4[i];
    row[4 * i + 0] = v.x;
    row[4 * i + 1] = v.y;
    row[4 * i + 2] = v.z;
    row[4 * i + 3] = v.w;
  }
  float4* o4 = (float4*)(tout + (size_t)n * 64);
#pragma unroll 1
  for (int pass = 0; pass < 4; pass++) {
    const float* Wp = W + pass * 16;   // cols [pass*16, pass*16+16)
    const float* bp = b + pass * 16;
    float acc[16];
#pragma unroll
    for (int c = 0; c < 16; c++) acc[c] = bp[c];  // uniform -> s_load
#pragma unroll
    for (int k = 0; k < 64; k++) {
      float hv = row[k];                  // VGPR (constant index)
      const float* wr = Wp + k * 64;      // 16 contiguous floats -> s_load_dwordx16
#pragma unroll
      for (int c = 0; c < 16; c++) acc[c] = fmaf(hv, wr[c], acc[c]);
    }
#pragma unroll
    for (int c4 = 0; c4 < 4; c4++) {
      o4[pass * 4 + c4] = make_float4(acc[4 * c4 + 0], acc[4 * c4 + 1],
                                      acc[4 * c4 + 2], acc[4 * c4 + 3]);
    }
  }
}

// ---------------- Aggregate: h = relu(sum_{e->n} norm*t[src] + t[n]/deg) ----------------
__global__ void k_aggregate(const float* __restrict__ t, const int* __restrict__ rp,
                            const int* __restrict__ csr_src, const float* __restrict__ csr_norm,
                            const float* __restrict__ inv_deg, float* __restrict__ hout) {
  int lane = threadIdx.x & 63;
  int n = blockIdx.x * 4 + (threadIdx.x >> 6);
  float acc = t[(size_t)n * 64 + lane] * inv_deg[n];
  int beg = rp[n], end = rp[n + 1];
  for (int idx = beg; idx < end; idx++) {
    int s = csr_src[idx];       // wave-uniform
    float w = csr_norm[idx];    // wave-uniform
    acc = fmaf(w, t[(size_t)s * 64 + lane], acc);  // coalesced 256B row gather
  }
  hout[(size_t)n * 64 + lane] = fmaxf(acc, 0.0f);
}

// ---------------- Readout: graph_ids sorted -> binary-search ranges ----------------
__global__ void k_readout(const float* __restrict__ h, const int* __restrict__ gids,
                          float* __restrict__ r) {
  int lane = threadIdx.x & 63;
  int g = blockIdx.x * 4 + (threadIdx.x >> 6);
  int lo = lowerBound(gids, NN, g);
  int hi = lowerBound(gids, NN, g + 1);
  float acc = 0.f;
  for (int n = lo; n < hi; n++) acc += h[(size_t)n * 64 + lane];
  r[(size_t)g * 64 + lane] = acc;
}

// ---------------- Dense head ----------------
// y1[g][j] = relu(b1[j] + sum_k concat(r,xa)[g][k] * W1[k][j]),  8 graphs/block
__global__ void __launch_bounds__(256) k_dense1(const float* __restrict__ r,
                                                const float* __restrict__ xa,
                                                const float* __restrict__ W1,
                                                const float* __restrict__ b1,
                                                float* __restrict__ y1) {
  __shared__ float xs[8 * 72];
  int tid = threadIdx.x;
  int g0 = blockIdx.x * 8;
  for (int i = tid; i < 8 * 72; i += 256) {
    int g = i / 72, k = i % 72;
    xs[i] = (k < 64) ? r[(size_t)(g0 + g) * 64 + k] : xa[(size_t)(g0 + g) * 8 + (k - 64)];
  }
  __syncthreads();
  float acc[8][2];
#pragma unroll
  for (int g = 0; g < 8; g++) { acc[g][0] = 0.f; acc[g][1] = 0.f; }
  for (int k = 0; k < 72; k++) {
    float w0 = W1[k * 512 + tid];
    float w1 = W1[k * 512 + 256 + tid];
#pragma unroll
    for (int g = 0; g < 8; g++) {
      float xv = xs[g * 72 + k];  // wave-uniform broadcast
      acc[g][0] = fmaf(xv, w0, acc[g][0]);
      acc[g][1] = fmaf(xv, w1, acc[g][1]);
    }
  }
  float bb0 = b1[tid], bb1 = b1[256 + tid];
#pragma unroll
  for (int g = 0; g < 8; g++) {
    y1[(size_t)(g0 + g) * 512 + tid]       = fmaxf(acc[g][0] + bb0, 0.f);
    y1[(size_t)(g0 + g) * 512 + 256 + tid] = fmaxf(acc[g][1] + bb1, 0.f);
  }
}

// y2 = relu(y1 @ W2 + b2), 16 graphs/block, k unrolled x4 with float4 LDS reads
__global__ void __launch_bounds__(256) k_dense2(const float* __restrict__ y1,
                                                const float* __restrict__ W2,
                                                const float* __restrict__ b2,
                                                float* __restrict__ y2) {
  __shared__ float ys[16 * 512];  // 32 KB
  int tid = threadIdx.x;
  int g0 = blockIdx.x * 16;
  for (int i = tid; i < 16 * 512; i += 256) ys[i] = y1[(size_t)g0 * 512 + i];
  __syncthreads();
  float acc[16][2];
#pragma unroll
  for (int g = 0; g < 16; g++) { acc[g][0] = 0.f; acc[g][1] = 0.f; }
  for (int k = 0; k < 512; k += 4) {
    float w0a = W2[(k + 0) * 512 + tid], w0b = W2[(k + 0) * 512 + 256 + tid];
    float w1a = W2[(k + 1) * 512 + tid], w1b = W2[(k + 1) * 512 + 256 + tid];
    float w2a = W2[(k + 2) * 512 + tid], w2b = W2[(k + 2) * 512 + 256 + tid];
    float w3a = W2[(k + 3) * 512 + tid], w3b = W2[(k + 3) * 512 + 256 + tid];
#pragma unroll
    for (int g = 0; g < 16; g++) {
      const float4 xv = *(const float4*)&ys[g * 512 + k];  // broadcast b128
      acc[g][0] = fmaf(xv.x, w0a, acc[g][0]);
      acc[g][0] = fmaf(xv.y, w1a, acc[g][0]);
      acc[g][0] = fmaf(xv.z, w2a, acc[g][0]);
      acc[g][0] = fmaf(xv.w, w3a, acc[g][0]);
      acc[g][1] = fmaf(xv.x, w0b, acc[g][1]);
      acc[g][1] = fmaf(xv.y, w1b, acc[g][1]);
      acc[g][1] = fmaf(xv.z, w2b, acc[g][1]);
      acc[g][1] = fmaf(xv.w, w3b, acc[g][1]);
    }
  }
  float bb0 = b2[tid], bb1 = b2[256 + tid];
#pragma unroll
  for (int g = 0; g < 16; g++) {
    y2[(size_t)(g0 + g) * 512 + tid]       = fmaxf(acc[g][0] + bb0, 0.f);
    y2[(size_t)(g0 + g) * 512 + 256 + tid] = fmaxf(acc[g][1] + bb1, 0.f);
  }
}

// out[g] = y2[g] . out_W + out_b   (wave per graph, shuffle reduce)
__global__ void k_out(const float* __restrict__ y2, const float* __restrict__ ow,
                      const float* __restrict__ ob, float* __restrict__ out) {
  int lane = threadIdx.x & 63;
  int g = blockIdx.x * 4 + (threadIdx.x >> 6);
  float s = 0.f;
#pragma unroll
  for (int j = 0; j < 8; j++) s = fmaf(y2[(size_t)g * 512 + j * 64 + lane], ow[j * 64 + lane], s);
#pragma unroll
  for (int off = 32; off > 0; off >>= 1) s += __shfl_down(s, off, 64);
  if (lane == 0) out[g] = s + ob[0];
}

extern "C" void kernel_launch(void* const* d_in, const int* in_sizes, int n_in,
                              void* d_out, int out_size, void* d_ws, size_t ws_size,
                              hipStream_t stream) {
  const float* x_mol    = (const float*)d_in[0];
  const float* x_adduct = (const float*)d_in[1];
  const int*   edge_src = (const int*)d_in[2];
  const int*   edge_dst = (const int*)d_in[3];
  const int*   graph_ids= (const int*)d_in[4];
  const float* gcn_W    = (const float*)d_in[5];
  const float* gcn_b    = (const float*)d_in[6];
  const float* d1W      = (const float*)d_in[7];
  const float* d1b      = (const float*)d_in[8];
  const float* d2W      = (const float*)d_in[9];
  const float* d2b      = (const float*)d_in[10];
  const float* oW       = (const float*)d_in[11];
  const float* obias    = (const float*)d_in[12];
  float* out = (float*)d_out;

  char* p = (char*)d_ws;
  auto alloc = [&](size_t bytes) {
    char* q = p;
    p += (bytes + 255) & ~(size_t)255;
    return q;
  };
  int*   counts   = (int*)alloc((size_t)NN * 4);
  int*   rp       = (int*)alloc((size_t)(NN + 1) * 4);
  int*   cursor   = (int*)alloc((size_t)NN * 4);
  int*   bsum     = (int*)alloc(1024 * 4);
  float* inv_deg  = (float*)alloc((size_t)NN * 4);
  int*   csr_src  = (int*)alloc((size_t)NE * 4);
  float* csr_norm = (float*)alloc((size_t)NE * 4);
  float* t        = (float*)alloc((size_t)NN * 64 * 4);
  float* h        = (float*)alloc((size_t)NN * 64 * 4);
  float* r        = (float*)alloc((size_t)NG * 64 * 4);
  float* y1       = (float*)alloc((size_t)NG * 512 * 4);
  float* y2       = (float*)alloc((size_t)NG * 512 * 4);

  hipMemsetAsync(counts, 0, (size_t)NN * 4, stream);
  k_count<<<NE / 256, 256, 0, stream>>>(edge_dst, counts);
  k_scan1<<<NN / 256, 256, 0, stream>>>(counts, rp, bsum);
  k_scan2<<<1, 1024, 0, stream>>>(bsum);
  k_scan3<<<NN / 256, 256, 0, stream>>>(counts, rp, bsum, cursor, inv_deg);
  k_fill<<<NE / 256, 256, 0, stream>>>(edge_src, edge_dst, counts, cursor, csr_src, csr_norm);

  const float* hin = x_mol;
  for (int L = 0; L < 3; L++) {
    k_transform<<<NN / 256, 256, 0, stream>>>(hin, gcn_W + (size_t)L * 64 * 64,
                                              gcn_b + (size_t)L * 64, t);
    k_aggregate<<<NN / 4, 256, 0, stream>>>(t, rp, csr_src, csr_norm, inv_deg, h);
    hin = h;
  }
  k_readout<<<NG / 4, 256, 0, stream>>>(h, graph_ids, r);
  k_dense1<<<NG / 8, 256, 0, stream>>>(r, x_adduct, d1W, d1b, y1);
  k_dense2<<<NG / 16, 256, 0, stream>>>(y1, d2W, d2b, y2);
  k_out<<<NG / 4, 256, 0, stream>>>(y2, oW, obias, out);
}

// Round 4
// 853.782 us; speedup vs baseline: 1.9555x; 1.9555x over previous
//
#include <hip/hip_runtime.h>

#define NN 262144   // nodes
#define NE 1048576  // edges
#define NG 8192     // graphs
#define FD 64       // feature dim
#define AD 8        // adduct dim
#define DN 512      // dense dim

__device__ __forceinline__ int lowerBound(const int* __restrict__ a, int n, int v) {
  int lo = 0, hi = n;
  while (lo < hi) { int mid = (lo + hi) >> 1; if (a[mid] < v) lo = mid + 1; else hi = mid; }
  return lo;
}

// ---------------- CSR build ----------------
__global__ void k_count(const int* __restrict__ dst, int* __restrict__ counts) {
  int e = blockIdx.x * 256 + threadIdx.x;
  if (e < NE) atomicAdd(&counts[dst[e]], 1);
}

__global__ void k_scan1(const int* __restrict__ counts, int* __restrict__ rp,
                        int* __restrict__ bsum) {
  __shared__ int s[256];
  int tid = threadIdx.x;
  int i = blockIdx.x * 256 + tid;
  int orig = counts[i];
  s[tid] = orig;
  __syncthreads();
  for (int off = 1; off < 256; off <<= 1) {
    int v = (tid >= off) ? s[tid - off] : 0;
    __syncthreads();
    s[tid] += v;
    __syncthreads();
  }
  rp[i] = s[tid] - orig;  // block-local exclusive scan
  if (tid == 255) bsum[blockIdx.x] = s[tid];
}

__global__ void k_scan2(int* __restrict__ bsum) {
  __shared__ int s[1024];
  int tid = threadIdx.x;
  int orig = bsum[tid];
  s[tid] = orig;
  __syncthreads();
  for (int off = 1; off < 1024; off <<= 1) {
    int v = (tid >= off) ? s[tid - off] : 0;
    __syncthreads();
    s[tid] += v;
    __syncthreads();
  }
  bsum[tid] = s[tid] - orig;  // exclusive
}

__global__ void k_scan3(const int* __restrict__ counts, int* __restrict__ rp,
                        const int* __restrict__ bsum, int* __restrict__ cursor,
                        float* __restrict__ inv_deg) {
  int i = blockIdx.x * 256 + threadIdx.x;
  int v = rp[i] + bsum[blockIdx.x];
  rp[i] = v;
  cursor[i] = v;
  inv_deg[i] = 1.0f / (float)(counts[i] + 1);
  if (i == 0) rp[NN] = NE;
}

__global__ void k_fill(const int* __restrict__ src, const int* __restrict__ dst,
                       const int* __restrict__ counts, int* __restrict__ cursor,
                       int* __restrict__ csr_src, float* __restrict__ csr_norm) {
  int e = blockIdx.x * 256 + threadIdx.x;
  if (e >= NE) return;
  int s = src[e], d = dst[e];
  float ds = (float)(counts[s] + 1);
  float dd = (float)(counts[d] + 1);
  int pos = atomicAdd(&cursor[d], 1);
  csr_src[pos] = s;
  csr_norm[pos] = rsqrtf(ds * dd);
}

// ---------------- GCN: t = h @ W + b ----------------
// Classic LDS-tiled GEMM. 64-node x 64-col tile per 256-thread block; each
// thread owns a 4x4 micro-tile (acc[4][4]: small, constant-indexed, SROA-safe
// -- the R2/R3 row[64]-in-registers structure spilled to scratch, never again).
// h staged TRANSPOSED (hsT[k][n], stride 68: 16B-aligned rows, non-pow2 bank
// stride) so the a-vector is one ds_read_b128; W staged as-is (b-vector is a
// contiguous ds_read_b128). Inner loop: 2 LDS b128 + 16 v_fmac per k.
#define HS 68  // hsT row stride (floats): 68*4=272 B, 16B-aligned, breaks pow2 banks
__global__ void __launch_bounds__(256) k_transform(const float* __restrict__ hin,
                                                   const float* __restrict__ W,
                                                   const float* __restrict__ b,
                                                   float* __restrict__ tout) {
  __shared__ float hsT[64 * HS];  // [k][n]  17.4 KB
  __shared__ float Ws[64 * 64];   // [k][c]  16 KB
  int tid = threadIdx.x;
  size_t base = (size_t)blockIdx.x * 64 * 64;

  // stage h-tile transposed: linear float4 reads (coalesced), scattered b32 writes
  const float4* h4 = (const float4*)(hin + base);
#pragma unroll
  for (int j = 0; j < 4; j++) {
    int f = tid + 256 * j;        // float4 index within 64x64 tile
    int n = f >> 4, kq = f & 15;  // node row, k-quad
    float4 v = h4[f];
    hsT[(4 * kq + 0) * HS + n] = v.x;
    hsT[(4 * kq + 1) * HS + n] = v.y;
    hsT[(4 * kq + 2) * HS + n] = v.z;
    hsT[(4 * kq + 3) * HS + n] = v.w;
  }
  // stage W straight (L2-resident after first block)
  const float4* w4 = (const float4*)W;
  float4* ws4 = (float4*)Ws;
#pragma unroll
  for (int j = 0; j < 4; j++) ws4[tid + 256 * j] = w4[tid + 256 * j];
  __syncthreads();

  int n0 = (tid >> 4) * 4;  // node quad (wave: 4 distinct -> 16-lane broadcast, free)
  int c0 = (tid & 15) * 4;  // col quad (wave: 16 contiguous float4s = 256B, free)
  float acc[4][4];
#pragma unroll
  for (int i = 0; i < 4; i++)
#pragma unroll
    for (int j = 0; j < 4; j++) acc[i][j] = b[c0 + j];

#pragma unroll 4
  for (int k = 0; k < 64; k++) {
    float4 av = *(const float4*)&hsT[k * HS + n0];  // ds_read_b128 (272B*k is 16B-mult)
    float4 bv = *(const float4*)&Ws[k * 64 + c0];   // ds_read_b128
    acc[0][0] = fmaf(av.x, bv.x, acc[0][0]);
    acc[0][1] = fmaf(av.x, bv.y, acc[0][1]);
    acc[0][2] = fmaf(av.x, bv.z, acc[0][2]);
    acc[0][3] = fmaf(av.x, bv.w, acc[0][3]);
    acc[1][0] = fmaf(av.y, bv.x, acc[1][0]);
    acc[1][1] = fmaf(av.y, bv.y, acc[1][1]);
    acc[1][2] = fmaf(av.y, bv.z, acc[1][2]);
    acc[1][3] = fmaf(av.y, bv.w, acc[1][3]);
    acc[2][0] = fmaf(av.z, bv.x, acc[2][0]);
    acc[2][1] = fmaf(av.z, bv.y, acc[2][1]);
    acc[2][2] = fmaf(av.z, bv.z, acc[2][2]);
    acc[2][3] = fmaf(av.z, bv.w, acc[2][3]);
    acc[3][0] = fmaf(av.w, bv.x, acc[3][0]);
    acc[3][1] = fmaf(av.w, bv.y, acc[3][1]);
    acc[3][2] = fmaf(av.w, bv.z, acc[3][2]);
    acc[3][3] = fmaf(av.w, bv.w, acc[3][3]);
  }

  float4* o4 = (float4*)(tout + base);
#pragma unroll
  for (int i = 0; i < 4; i++) {
    o4[((n0 + i) * 64 + c0) >> 2] =
        make_float4(acc[i][0], acc[i][1], acc[i][2], acc[i][3]);
  }
}

// ---------------- Aggregate: h = relu(sum_{e->n} norm*t[src] + t[n]/deg) ----------------
__global__ void k_aggregate(const float* __restrict__ t, const int* __restrict__ rp,
                            const int* __restrict__ csr_src, const float* __restrict__ csr_norm,
                            const float* __restrict__ inv_deg, float* __restrict__ hout) {
  int lane = threadIdx.x & 63;
  int n = blockIdx.x * 4 + (threadIdx.x >> 6);
  float acc = t[(size_t)n * 64 + lane] * inv_deg[n];
  int beg = rp[n], end = rp[n + 1];
  for (int idx = beg; idx < end; idx++) {
    int s = csr_src[idx];       // wave-uniform
    float w = csr_norm[idx];    // wave-uniform
    acc = fmaf(w, t[(size_t)s * 64 + lane], acc);  // coalesced 256B row gather
  }
  hout[(size_t)n * 64 + lane] = fmaxf(acc, 0.0f);
}

// ---------------- Readout: graph_ids sorted -> binary-search ranges ----------------
__global__ void k_readout(const float* __restrict__ h, const int* __restrict__ gids,
                          float* __restrict__ r) {
  int lane = threadIdx.x & 63;
  int g = blockIdx.x * 4 + (threadIdx.x >> 6);
  int lo = lowerBound(gids, NN, g);
  int hi = lowerBound(gids, NN, g + 1);
  float acc = 0.f;
  for (int n = lo; n < hi; n++) acc += h[(size_t)n * 64 + lane];
  r[(size_t)g * 64 + lane] = acc;
}

// ---------------- Dense head ----------------
// y1[g][j] = relu(b1[j] + sum_k concat(r,xa)[g][k] * W1[k][j]),  8 graphs/block
__global__ void __launch_bounds__(256) k_dense1(const float* __restrict__ r,
                                                const float* __restrict__ xa,
                                                const float* __restrict__ W1,
                                                const float* __restrict__ b1,
                                                float* __restrict__ y1) {
  __shared__ float xs[8 * 72];
  int tid = threadIdx.x;
  int g0 = blockIdx.x * 8;
  for (int i = tid; i < 8 * 72; i += 256) {
    int g = i / 72, k = i % 72;
    xs[i] = (k < 64) ? r[(size_t)(g0 + g) * 64 + k] : xa[(size_t)(g0 + g) * 8 + (k - 64)];
  }
  __syncthreads();
  float acc[8][2];
#pragma unroll
  for (int g = 0; g < 8; g++) { acc[g][0] = 0.f; acc[g][1] = 0.f; }
  for (int k = 0; k < 72; k++) {
    float w0 = W1[k * 512 + tid];
    float w1 = W1[k * 512 + 256 + tid];
#pragma unroll
    for (int g = 0; g < 8; g++) {
      float xv = xs[g * 72 + k];  // wave-uniform broadcast
      acc[g][0] = fmaf(xv, w0, acc[g][0]);
      acc[g][1] = fmaf(xv, w1, acc[g][1]);
    }
  }
  float bb0 = b1[tid], bb1 = b1[256 + tid];
#pragma unroll
  for (int g = 0; g < 8; g++) {
    y1[(size_t)(g0 + g) * 512 + tid]       = fmaxf(acc[g][0] + bb0, 0.f);
    y1[(size_t)(g0 + g) * 512 + 256 + tid] = fmaxf(acc[g][1] + bb1, 0.f);
  }
}

// y2 = relu(y1 @ W2 + b2), 16 graphs/block, k unrolled x4 with float4 LDS reads
__global__ void __launch_bounds__(256) k_dense2(const float* __restrict__ y1,
                                                const float* __restrict__ W2,
                                                const float* __restrict__ b2,
                                                float* __restrict__ y2) {
  __shared__ float ys[16 * 512];  // 32 KB
  int tid = threadIdx.x;
  int g0 = blockIdx.x * 16;
  for (int i = tid; i < 16 * 512; i += 256) ys[i] = y1[(size_t)g0 * 512 + i];
  __syncthreads();
  float acc[16][2];
#pragma unroll
  for (int g = 0; g < 16; g++) { acc[g][0] = 0.f; acc[g][1] = 0.f; }
  for (int k = 0; k < 512; k += 4) {
    float w0a = W2[(k + 0) * 512 + tid], w0b = W2[(k + 0) * 512 + 256 + tid];
    float w1a = W2[(k + 1) * 512 + tid], w1b = W2[(k + 1) * 512 + 256 + tid];
    float w2a = W2[(k + 2) * 512 + tid], w2b = W2[(k + 2) * 512 + 256 + tid];
    float w3a = W2[(k + 3) * 512 + tid], w3b = W2[(k + 3) * 512 + 256 + tid];
#pragma unroll
    for (int g = 0; g < 16; g++) {
      const float4 xv = *(const float4*)&ys[g * 512 + k];  // broadcast b128
      acc[g][0] = fmaf(xv.x, w0a, acc[g][0]);
      acc[g][0] = fmaf(xv.y, w1a, acc[g][0]);
      acc[g][0] = fmaf(xv.z, w2a, acc[g][0]);
      acc[g][0] = fmaf(xv.w, w3a, acc[g][0]);
      acc[g][1] = fmaf(xv.x, w0b, acc[g][1]);
      acc[g][1] = fmaf(xv.y, w1b, acc[g][1]);
      acc[g][1] = fmaf(xv.z, w2b, acc[g][1]);
      acc[g][1] = fmaf(xv.w, w3b, acc[g][1]);
    }
  }
  float bb0 = b2[tid], bb1 = b2[256 + tid];
#pragma unroll
  for (int g = 0; g < 16; g++) {
    y2[(size_t)(g0 + g) * 512 + tid]       = fmaxf(acc[g][0] + bb0, 0.f);
    y2[(size_t)(g0 + g) * 512 + 256 + tid] = fmaxf(acc[g][1] + bb1, 0.f);
  }
}

// out[g] = y2[g] . out_W + out_b   (wave per graph, shuffle reduce)
__global__ void k_out(const float* __restrict__ y2, const float* __restrict__ ow,
                      const float* __restrict__ ob, float* __restrict__ out) {
  int lane = threadIdx.x & 63;
  int g = blockIdx.x * 4 + (threadIdx.x >> 6);
  float s = 0.f;
#pragma unroll
  for (int j = 0; j < 8; j++) s = fmaf(y2[(size_t)g * 512 + j * 64 + lane], ow[j * 64 + lane], s);
#pragma unroll
  for (int off = 32; off > 0; off >>= 1) s += __shfl_down(s, off, 64);
  if (lane == 0) out[g] = s + ob[0];
}

extern "C" void kernel_launch(void* const* d_in, const int* in_sizes, int n_in,
                              void* d_out, int out_size, void* d_ws, size_t ws_size,
                              hipStream_t stream) {
  const float* x_mol    = (const float*)d_in[0];
  const float* x_adduct = (const float*)d_in[1];
  const int*   edge_src = (const int*)d_in[2];
  const int*   edge_dst = (const int*)d_in[3];
  const int*   graph_ids= (const int*)d_in[4];
  const float* gcn_W    = (const float*)d_in[5];
  const float* gcn_b    = (const float*)d_in[6];
  const float* d1W      = (const float*)d_in[7];
  const float* d1b      = (const float*)d_in[8];
  const float* d2W      = (const float*)d_in[9];
  const float* d2b      = (const float*)d_in[10];
  const float* oW       = (const float*)d_in[11];
  const float* obias    = (const float*)d_in[12];
  float* out = (float*)d_out;

  char* p = (char*)d_ws;
  auto alloc = [&](size_t bytes) {
    char* q = p;
    p += (bytes + 255) & ~(size_t)255;
    return q;
  };
  int*   counts   = (int*)alloc((size_t)NN * 4);
  int*   rp       = (int*)alloc((size_t)(NN + 1) * 4);
  int*   cursor   = (int*)alloc((size_t)NN * 4);
  int*   bsum     = (int*)alloc(1024 * 4);
  float* inv_deg  = (float*)alloc((size_t)NN * 4);
  int*   csr_src  = (int*)alloc((size_t)NE * 4);
  float* csr_norm = (float*)alloc((size_t)NE * 4);
  float* t        = (float*)alloc((size_t)NN * 64 * 4);
  float* h        = (float*)alloc((size_t)NN * 64 * 4);
  float* r        = (float*)alloc((size_t)NG * 64 * 4);
  float* y1       = (float*)alloc((size_t)NG * 512 * 4);
  float* y2       = (float*)alloc((size_t)NG * 512 * 4);

  hipMemsetAsync(counts, 0, (size_t)NN * 4, stream);
  k_count<<<NE / 256, 256, 0, stream>>>(edge_dst, counts);
  k_scan1<<<NN / 256, 256, 0, stream>>>(counts, rp, bsum);
  k_scan2<<<1, 1024, 0, stream>>>(bsum);
  k_scan3<<<NN / 256, 256, 0, stream>>>(counts, rp, bsum, cursor, inv_deg);
  k_fill<<<NE / 256, 256, 0, stream>>>(edge_src, edge_dst, counts, cursor, csr_src, csr_norm);

  const float* hin = x_mol;
  for (int L = 0; L < 3; L++) {
    k_transform<<<NN / 64, 256, 0, stream>>>(hin, gcn_W + (size_t)L * 64 * 64,
                                             gcn_b + (size_t)L * 64, t);
    k_aggregate<<<NN / 4, 256, 0, stream>>>(t, rp, csr_src, csr_norm, inv_deg, h);
    hin = h;
  }
  k_readout<<<NG / 4, 256, 0, stream>>>(h, graph_ids, r);
  k_dense1<<<NG / 8, 256, 0, stream>>>(r, x_adduct, d1W, d1b, y1);
  k_dense2<<<NG / 16, 256, 0, stream>>>(y1, d2W, d2b, y2);
  k_out<<<NG / 4, 256, 0, stream>>>(y2, oW, obias, out);
}

// Round 5
// 722.429 us; speedup vs baseline: 2.3111x; 1.1818x over previous
//
#include <hip/hip_runtime.h>

#define NN 262144   // nodes
#define NE 1048576  // edges
#define NG 8192     // graphs
#define FD 64       // feature dim
#define AD 8        // adduct dim
#define DN 512      // dense dim

__device__ __forceinline__ int lowerBound(const int* __restrict__ a, int n, int v) {
  int lo = 0, hi = n;
  while (lo < hi) { int mid = (lo + hi) >> 1; if (a[mid] < v) lo = mid + 1; else hi = mid; }
  return lo;
}

// ---------------- CSR build ----------------
__global__ void k_count(const int* __restrict__ dst, int* __restrict__ counts) {
  int e = blockIdx.x * 256 + threadIdx.x;
  if (e < NE) atomicAdd(&counts[dst[e]], 1);
}

__global__ void k_scan1(const int* __restrict__ counts, int* __restrict__ rp,
                        int* __restrict__ bsum) {
  __shared__ int s[256];
  int tid = threadIdx.x;
  int i = blockIdx.x * 256 + tid;
  int orig = counts[i];
  s[tid] = orig;
  __syncthreads();
  for (int off = 1; off < 256; off <<= 1) {
    int v = (tid >= off) ? s[tid - off] : 0;
    __syncthreads();
    s[tid] += v;
    __syncthreads();
  }
  rp[i] = s[tid] - orig;  // block-local exclusive scan
  if (tid == 255) bsum[blockIdx.x] = s[tid];
}

__global__ void k_scan2(int* __restrict__ bsum) {
  __shared__ int s[1024];
  int tid = threadIdx.x;
  int orig = bsum[tid];
  s[tid] = orig;
  __syncthreads();
  for (int off = 1; off < 1024; off <<= 1) {
    int v = (tid >= off) ? s[tid - off] : 0;
    __syncthreads();
    s[tid] += v;
    __syncthreads();
  }
  bsum[tid] = s[tid] - orig;  // exclusive
}

__global__ void k_scan3(const int* __restrict__ counts, int* __restrict__ rp,
                        const int* __restrict__ bsum, int* __restrict__ cursor,
                        float* __restrict__ inv_deg) {
  int i = blockIdx.x * 256 + threadIdx.x;
  int v = rp[i] + bsum[blockIdx.x];
  rp[i] = v;
  cursor[i] = v;
  inv_deg[i] = 1.0f / (float)(counts[i] + 1);
  if (i == 0) rp[NN] = NE;
}

__global__ void k_fill(const int* __restrict__ src, const int* __restrict__ dst,
                       const int* __restrict__ counts, int* __restrict__ cursor,
                       int* __restrict__ csr_src, float* __restrict__ csr_norm) {
  int e = blockIdx.x * 256 + threadIdx.x;
  if (e >= NE) return;
  int s = src[e], d = dst[e];
  float ds = (float)(counts[s] + 1);
  float dd = (float)(counts[d] + 1);
  int pos = atomicAdd(&cursor[d], 1);
  csr_src[pos] = s;
  csr_norm[pos] = rsqrtf(ds * dd);
}

// ---------------- GCN: t = h @ W + b ----------------
// Classic LDS-tiled GEMM (validated R4: ~28 us/layer, no scratch traffic).
#define HS 68  // hsT row stride (floats): 68*4=272 B, 16B-aligned, breaks pow2 banks
__global__ void __launch_bounds__(256) k_transform(const float* __restrict__ hin,
                                                   const float* __restrict__ W,
                                                   const float* __restrict__ b,
                                                   float* __restrict__ tout) {
  __shared__ float hsT[64 * HS];  // [k][n]  17.4 KB
  __shared__ float Ws[64 * 64];   // [k][c]  16 KB
  int tid = threadIdx.x;
  size_t base = (size_t)blockIdx.x * 64 * 64;

  const float4* h4 = (const float4*)(hin + base);
#pragma unroll
  for (int j = 0; j < 4; j++) {
    int f = tid + 256 * j;        // float4 index within 64x64 tile
    int n = f >> 4, kq = f & 15;  // node row, k-quad
    float4 v = h4[f];
    hsT[(4 * kq + 0) * HS + n] = v.x;
    hsT[(4 * kq + 1) * HS + n] = v.y;
    hsT[(4 * kq + 2) * HS + n] = v.z;
    hsT[(4 * kq + 3) * HS + n] = v.w;
  }
  const float4* w4 = (const float4*)W;
  float4* ws4 = (float4*)Ws;
#pragma unroll
  for (int j = 0; j < 4; j++) ws4[tid + 256 * j] = w4[tid + 256 * j];
  __syncthreads();

  int n0 = (tid >> 4) * 4;  // node quad (16-lane broadcast, free)
  int c0 = (tid & 15) * 4;  // col quad (contiguous 256B, free)
  float acc[4][4];
#pragma unroll
  for (int i = 0; i < 4; i++)
#pragma unroll
    for (int j = 0; j < 4; j++) acc[i][j] = b[c0 + j];

#pragma unroll 4
  for (int k = 0; k < 64; k++) {
    float4 av = *(const float4*)&hsT[k * HS + n0];  // ds_read_b128
    float4 bv = *(const float4*)&Ws[k * 64 + c0];   // ds_read_b128
    acc[0][0] = fmaf(av.x, bv.x, acc[0][0]);
    acc[0][1] = fmaf(av.x, bv.y, acc[0][1]);
    acc[0][2] = fmaf(av.x, bv.z, acc[0][2]);
    acc[0][3] = fmaf(av.x, bv.w, acc[0][3]);
    acc[1][0] = fmaf(av.y, bv.x, acc[1][0]);
    acc[1][1] = fmaf(av.y, bv.y, acc[1][1]);
    acc[1][2] = fmaf(av.y, bv.z, acc[1][2]);
    acc[1][3] = fmaf(av.y, bv.w, acc[1][3]);
    acc[2][0] = fmaf(av.z, bv.x, acc[2][0]);
    acc[2][1] = fmaf(av.z, bv.y, acc[2][1]);
    acc[2][2] = fmaf(av.z, bv.z, acc[2][2]);
    acc[2][3] = fmaf(av.z, bv.w, acc[2][3]);
    acc[3][0] = fmaf(av.w, bv.x, acc[3][0]);
    acc[3][1] = fmaf(av.w, bv.y, acc[3][1]);
    acc[3][2] = fmaf(av.w, bv.z, acc[3][2]);
    acc[3][3] = fmaf(av.w, bv.w, acc[3][3]);
  }

  float4* o4 = (float4*)(tout + base);
#pragma unroll
  for (int i = 0; i < 4; i++) {
    o4[((n0 + i) * 64 + c0) >> 2] =
        make_float4(acc[i][0], acc[i][1], acc[i][2], acc[i][3]);
  }
}

// ---------------- Aggregate: h = relu(sum_{e->n} norm*t[src] + t[n]/deg) ----------------
// R4 was latency-bound on the serialized chain (idx load -> gather) x deg.
// Unroll 4 with INDEPENDENT accumulators: all 4 src/norm loads issue at once
// (contiguous indices), then all 4 row gathers are in flight simultaneously.
__global__ void k_aggregate(const float* __restrict__ t, const int* __restrict__ rp,
                            const int* __restrict__ csr_src, const float* __restrict__ csr_norm,
                            const float* __restrict__ inv_deg, float* __restrict__ hout) {
  int lane = threadIdx.x & 63;
  int n = blockIdx.x * 4 + (threadIdx.x >> 6);
  int beg = rp[n], end = rp[n + 1];
  float a0 = t[(size_t)n * 64 + lane] * inv_deg[n];
  float a1 = 0.f, a2 = 0.f, a3 = 0.f;
  int idx = beg;
  for (; idx + 4 <= end; idx += 4) {
    int s0 = csr_src[idx + 0];
    int s1 = csr_src[idx + 1];
    int s2 = csr_src[idx + 2];
    int s3 = csr_src[idx + 3];
    float w0 = csr_norm[idx + 0];
    float w1 = csr_norm[idx + 1];
    float w2 = csr_norm[idx + 2];
    float w3 = csr_norm[idx + 3];
    a0 = fmaf(w0, t[(size_t)s0 * 64 + lane], a0);
    a1 = fmaf(w1, t[(size_t)s1 * 64 + lane], a1);
    a2 = fmaf(w2, t[(size_t)s2 * 64 + lane], a2);
    a3 = fmaf(w3, t[(size_t)s3 * 64 + lane], a3);
  }
  for (; idx < end; idx++) {
    int s = csr_src[idx];
    float w = csr_norm[idx];
    a0 = fmaf(w, t[(size_t)s * 64 + lane], a0);
  }
  hout[(size_t)n * 64 + lane] = fmaxf((a0 + a1) + (a2 + a3), 0.0f);
}

// ---------------- Readout: graph_ids sorted -> binary-search ranges ----------------
__global__ void k_readout(const float* __restrict__ h, const int* __restrict__ gids,
                          float* __restrict__ r) {
  int lane = threadIdx.x & 63;
  int g = blockIdx.x * 4 + (threadIdx.x >> 6);
  int lo = lowerBound(gids, NN, g);
  int hi = lowerBound(gids, NN, g + 1);
  float acc = 0.f;
  for (int n = lo; n < hi; n++) acc += h[(size_t)n * 64 + lane];
  r[(size_t)g * 64 + lane] = acc;
}

// ---------------- Dense head ----------------
// y1[g][j] = relu(b1[j] + sum_k concat(r,xa)[g][k] * W1[k][j]),  8 graphs/block
__global__ void __launch_bounds__(256) k_dense1(const float* __restrict__ r,
                                                const float* __restrict__ xa,
                                                const float* __restrict__ W1,
                                                const float* __restrict__ b1,
                                                float* __restrict__ y1) {
  __shared__ float xs[8 * 72];
  int tid = threadIdx.x;
  int g0 = blockIdx.x * 8;
  for (int i = tid; i < 8 * 72; i += 256) {
    int g = i / 72, k = i % 72;
    xs[i] = (k < 64) ? r[(size_t)(g0 + g) * 64 + k] : xa[(size_t)(g0 + g) * 8 + (k - 64)];
  }
  __syncthreads();
  float acc[8][2];
#pragma unroll
  for (int g = 0; g < 8; g++) { acc[g][0] = 0.f; acc[g][1] = 0.f; }
  for (int k = 0; k < 72; k++) {
    float w0 = W1[k * 512 + tid];
    float w1 = W1[k * 512 + 256 + tid];
#pragma unroll
    for (int g = 0; g < 8; g++) {
      float xv = xs[g * 72 + k];  // wave-uniform broadcast
      acc[g][0] = fmaf(xv, w0, acc[g][0]);
      acc[g][1] = fmaf(xv, w1, acc[g][1]);
    }
  }
  float bb0 = b1[tid], bb1 = b1[256 + tid];
#pragma unroll
  for (int g = 0; g < 8; g++) {
    y1[(size_t)(g0 + g) * 512 + tid]       = fmaxf(acc[g][0] + bb0, 0.f);
    y1[(size_t)(g0 + g) * 512 + 256 + tid] = fmaxf(acc[g][1] + bb1, 0.f);
  }
}

// y2 = relu(y1 @ W2 + b2), 16 graphs/block, k unrolled x4 with float4 LDS reads
__global__ void __launch_bounds__(256) k_dense2(const float* __restrict__ y1,
                                                const float* __restrict__ W2,
                                                const float* __restrict__ b2,
                                                float* __restrict__ y2) {
  __shared__ float ys[16 * 512];  // 32 KB
  int tid = threadIdx.x;
  int g0 = blockIdx.x * 16;
  for (int i = tid; i < 16 * 512; i += 256) ys[i] = y1[(size_t)g0 * 512 + i];
  __syncthreads();
  float acc[16][2];
#pragma unroll
  for (int g = 0; g < 16; g++) { acc[g][0] = 0.f; acc[g][1] = 0.f; }
  for (int k = 0; k < 512; k += 4) {
    float w0a = W2[(k + 0) * 512 + tid], w0b = W2[(k + 0) * 512 + 256 + tid];
    float w1a = W2[(k + 1) * 512 + tid], w1b = W2[(k + 1) * 512 + 256 + tid];
    float w2a = W2[(k + 2) * 512 + tid], w2b = W2[(k + 2) * 512 + 256 + tid];
    float w3a = W2[(k + 3) * 512 + tid], w3b = W2[(k + 3) * 512 + 256 + tid];
#pragma unroll
    for (int g = 0; g < 16; g++) {
      const float4 xv = *(const float4*)&ys[g * 512 + k];  // broadcast b128
      acc[g][0] = fmaf(xv.x, w0a, acc[g][0]);
      acc[g][0] = fmaf(xv.y, w1a, acc[g][0]);
      acc[g][0] = fmaf(xv.z, w2a, acc[g][0]);
      acc[g][0] = fmaf(xv.w, w3a, acc[g][0]);
      acc[g][1] = fmaf(xv.x, w0b, acc[g][1]);
      acc[g][1] = fmaf(xv.y, w1b, acc[g][1]);
      acc[g][1] = fmaf(xv.z, w2b, acc[g][1]);
      acc[g][1] = fmaf(xv.w, w3b, acc[g][1]);
    }
  }
  float bb0 = b2[tid], bb1 = b2[256 + tid];
#pragma unroll
  for (int g = 0; g < 16; g++) {
    y2[(size_t)(g0 + g) * 512 + tid]       = fmaxf(acc[g][0] + bb0, 0.f);
    y2[(size_t)(g0 + g) * 512 + 256 + tid] = fmaxf(acc[g][1] + bb1, 0.f);
  }
}

// out[g] = y2[g] . out_W + out_b   (wave per graph, shuffle reduce)
__global__ void k_out(const float* __restrict__ y2, const float* __restrict__ ow,
                      const float* __restrict__ ob, float* __restrict__ out) {
  int lane = threadIdx.x & 63;
  int g = blockIdx.x * 4 + (threadIdx.x >> 6);
  float s = 0.f;
#pragma unroll
  for (int j = 0; j < 8; j++) s = fmaf(y2[(size_t)g * 512 + j * 64 + lane], ow[j * 64 + lane], s);
#pragma unroll
  for (int off = 32; off > 0; off >>= 1) s += __shfl_down(s, off, 64);
  if (lane == 0) out[g] = s + ob[0];
}

extern "C" void kernel_launch(void* const* d_in, const int* in_sizes, int n_in,
                              void* d_out, int out_size, void* d_ws, size_t ws_size,
                              hipStream_t stream) {
  const float* x_mol    = (const float*)d_in[0];
  const float* x_adduct = (const float*)d_in[1];
  const int*   edge_src = (const int*)d_in[2];
  const int*   edge_dst = (const int*)d_in[3];
  const int*   graph_ids= (const int*)d_in[4];
  const float* gcn_W    = (const float*)d_in[5];
  const float* gcn_b    = (const float*)d_in[6];
  const float* d1W      = (const float*)d_in[7];
  const float* d1b      = (const float*)d_in[8];
  const float* d2W      = (const float*)d_in[9];
  const float* d2b      = (const float*)d_in[10];
  const float* oW       = (const float*)d_in[11];
  const float* obias    = (const float*)d_in[12];
  float* out = (float*)d_out;

  char* p = (char*)d_ws;
  auto alloc = [&](size_t bytes) {
    char* q = p;
    p += (bytes + 255) & ~(size_t)255;
    return q;
  };
  int*   counts   = (int*)alloc((size_t)NN * 4);
  int*   rp       = (int*)alloc((size_t)(NN + 1) * 4);
  int*   cursor   = (int*)alloc((size_t)NN * 4);
  int*   bsum     = (int*)alloc(1024 * 4);
  float* inv_deg  = (float*)alloc((size_t)NN * 4);
  int*   csr_src  = (int*)alloc((size_t)NE * 4);
  float* csr_norm = (float*)alloc((size_t)NE * 4);
  float* t        = (float*)alloc((size_t)NN * 64 * 4);
  float* h        = (float*)alloc((size_t)NN * 64 * 4);
  float* r        = (float*)alloc((size_t)NG * 64 * 4);
  float* y1       = (float*)alloc((size_t)NG * 512 * 4);
  float* y2       = (float*)alloc((size_t)NG * 512 * 4);

  hipMemsetAsync(counts, 0, (size_t)NN * 4, stream);
  k_count<<<NE / 256, 256, 0, stream>>>(edge_dst, counts);
  k_scan1<<<NN / 256, 256, 0, stream>>>(counts, rp, bsum);
  k_scan2<<<1, 1024, 0, stream>>>(bsum);
  k_scan3<<<NN / 256, 256, 0, stream>>>(counts, rp, bsum, cursor, inv_deg);
  k_fill<<<NE / 256, 256, 0, stream>>>(edge_src, edge_dst, counts, cursor, csr_src, csr_norm);

  const float* hin = x_mol;
  for (int L = 0; L < 3; L++) {
    k_transform<<<NN / 64, 256, 0, stream>>>(hin, gcn_W + (size_t)L * 64 * 64,
                                             gcn_b + (size_t)L * 64, t);
    k_aggregate<<<NN / 4, 256, 0, stream>>>(t, rp, csr_src, csr_norm, inv_deg, h);
    hin = h;
  }
  k_readout<<<NG / 4, 256, 0, stream>>>(h, graph_ids, r);
  k_dense1<<<NG / 8, 256, 0, stream>>>(r, x_adduct, d1W, d1b, y1);
  k_dense2<<<NG / 16, 256, 0, stream>>>(y1, d2W, d2b, y2);
  k_out<<<NG / 4, 256, 0, stream>>>(y2, oW, obias, out);
}